// Round 1
// baseline (898.203 us; speedup 1.0000x reference)
//
#include <hip/hip_runtime.h>
#include <hip/hip_bf16.h>

typedef unsigned short u16;
typedef unsigned int u32;
typedef __attribute__((ext_vector_type(8))) short s16x8;
typedef __attribute__((ext_vector_type(4))) float f32x4;
typedef __attribute__((ext_vector_type(2))) float f32x2;
typedef __attribute__((ext_vector_type(4))) unsigned short u16x4;

#define DEV static __device__ __forceinline__

// ---------- helpers ----------
DEV u16 bf16_rne(float f) {
  u32 u = __float_as_uint(f);
  u32 r = 0x7FFFu + ((u >> 16) & 1u);
  return (u16)((u + r) >> 16);
}
DEV float bf16_to_f32(u16 h) { return __uint_as_float(((u32)h) << 16); }

typedef const __attribute__((address_space(1))) u32* gptr_t;
typedef __attribute__((address_space(3))) u32* lptr_t;
DEV void gload_lds16(const void* g, void* l) {
  __builtin_amdgcn_global_load_lds((gptr_t)g, (lptr_t)l, 16, 0, 0);
}

// ---------- workspace layout (bytes) ----------
#define OFF_XSPLIT  0ull                       // 2 * 4096*2048 u16 = 33,554,432   (Xh | Xl)
#define OFF_WSPLIT  33554432ull                // 2 * 6144*2048 u16 = 50,331,648   (Wh | Wl) ; reused later for (Ph | Pl)
#define OFF_QKF     83886080ull                // 4096*4096 f32 = 67,108,864       ([q|k] fp32 per row)
#define OFF_VB      150994944ull               // 4096*2048 u16 = 16,777,216       v bf16 (n,h,d)
#define OFF_QB      167772160ull               // 16,777,216                       q bf16 (h,n,d)
#define OFF_KB      184549376ull               // 16,777,216                       k bf16 (h,n,d)
#define OFF_VT      201326592ull               // 16,777,216                       v bf16 (h,d,n)
#define OFF_COS     218103808ull               // 4096*64 f32 = 1,048,576
#define OFF_SIN     219152384ull               // 1,048,576
// OBF (attention out bf16, (n,2048)) reuses OFF_XSPLIT (x dead after QKV GEMM)

// ---------- split fp32 -> bf16 hi + bf16 lo ----------
__global__ __launch_bounds__(256) void k_split(const float* __restrict__ in,
                                               u16* __restrict__ hi, u16* __restrict__ lo, int n) {
  int i = blockIdx.x * 256 + threadIdx.x;
  int stride = gridDim.x * 256;
  for (; i < n; i += stride) {
    float x = in[i];
    u16 h = bf16_rne(x);
    float xh = bf16_to_f32(h);
    hi[i] = h;
    lo[i] = bf16_rne(x - xh);
  }
}

// ---------- RoPE cos/sin table: (n, 64) ----------
__global__ __launch_bounds__(256) void k_rope_table(float* __restrict__ cosT, float* __restrict__ sinT) {
  int tid = blockIdx.x * 256 + threadIdx.x;
  if (tid >= 4096 * 64) return;
  int n = tid >> 6, j = tid & 63;
  int t = n >> 9, hh = (n >> 5) & 15, ww = n & 31;
  float pos, e;
  if (j < 32)      { pos = (float)t;  e = (float)j * (1.0f / 32.0f); }
  else if (j < 48) { pos = (float)hh; e = (float)(j - 32) * (1.0f / 16.0f); }
  else             { pos = (float)ww; e = (float)(j - 48) * (1.0f / 16.0f); }
  float inv = (float)pow(10000.0, -(double)e);
  float f = pos * inv;
  cosT[tid] = cosf(f);
  sinT[tid] = sinf(f);
}

// ---------- bf16 GEMM, m97 structure: 128x128 tile, BK=32, 4 waves ----------
// C[M][?] = sum_seg A_seg (Mx K, row-major) . B_seg^T (Nc x K, row-major), fp32 acc.
// MODE 0: QKV epilogue (cols 0..4095 -> fp32 qk buffer, cols 4096.. -> bf16 v buffer)
// MODE 1: proj epilogue (fp32 out)
template<int MODE>
__global__ __launch_bounds__(256, 2) void k_gemm(
    const u16* __restrict__ A0, const u16* __restrict__ A1, const u16* __restrict__ A2,
    const u16* __restrict__ B0, const u16* __restrict__ B1, const u16* __restrict__ B2,
    int nseg, int K,
    const float* __restrict__ bias,
    float* __restrict__ outF, u16* __restrict__ outV)
{
  __shared__ u16 As[128 * 32];
  __shared__ u16 Bs[128 * 32];
  const int t = threadIdx.x;
  const int lane = t & 63;
  const int lr = lane & 15, lg = lane >> 4;
  const int w = t >> 6;
  const int wr = w >> 1, wc = w & 1;
  const int row0 = blockIdx.y * 128;
  const int col0 = blockIdx.x * 128;

  f32x4 acc[4][4];
#pragma unroll
  for (int m = 0; m < 4; m++)
#pragma unroll
    for (int n = 0; n < 4; n++) acc[m][n] = f32x4{0.f, 0.f, 0.f, 0.f};

  const int c0 = t, c1 = t + 256;   // chunk ids; chunk c -> row c>>2, k-part (c&3)*8, lds ushort off c*8

  for (int s = 0; s < nseg; ++s) {
    const u16* Ab = (s == 0) ? A0 : (s == 1) ? A1 : A2;
    const u16* Bb = (s == 0) ? B0 : (s == 1) ? B1 : B2;
    const int nkb = K / 32;
    for (int kb = 0; kb < nkb; ++kb) {
      const int k0 = kb * 32;
      gload_lds16(Ab + (size_t)(row0 + (c0 >> 2)) * K + k0 + (c0 & 3) * 8, &As[c0 * 8]);
      gload_lds16(Ab + (size_t)(row0 + (c1 >> 2)) * K + k0 + (c1 & 3) * 8, &As[c1 * 8]);
      gload_lds16(Bb + (size_t)(col0 + (c0 >> 2)) * K + k0 + (c0 & 3) * 8, &Bs[c0 * 8]);
      gload_lds16(Bb + (size_t)(col0 + (c1 >> 2)) * K + k0 + (c1 & 3) * 8, &Bs[c1 * 8]);
      __syncthreads();
      s16x8 af[4], bf[4];
#pragma unroll
      for (int m = 0; m < 4; m++)
        af[m] = *(const s16x8*)&As[(wr * 64 + m * 16 + lr) * 32 + lg * 8];
#pragma unroll
      for (int n = 0; n < 4; n++)
        bf[n] = *(const s16x8*)&Bs[(wc * 64 + n * 16 + lr) * 32 + lg * 8];
#pragma unroll
      for (int m = 0; m < 4; m++)
#pragma unroll
        for (int n = 0; n < 4; n++)
          acc[m][n] = __builtin_amdgcn_mfma_f32_16x16x32_bf16(af[m], bf[n], acc[m][n], 0, 0, 0);
      __syncthreads();
    }
  }

#pragma unroll
  for (int m = 0; m < 4; m++) {
#pragma unroll
    for (int n = 0; n < 4; n++) {
      int col = col0 + wc * 64 + n * 16 + lr;
      float b = bias[col];
#pragma unroll
      for (int r = 0; r < 4; r++) {
        int row = row0 + wr * 64 + m * 16 + lg * 4 + r;
        float v = acc[m][n][r] + b;
        if constexpr (MODE == 0) {
          if (col < 4096) outF[(size_t)row * 4096 + col] = v;
          else            outV[(size_t)row * 2048 + (col - 4096)] = bf16_rne(v);
        } else {
          outF[(size_t)row * 2048 + col] = v;
        }
      }
    }
  }
}

// ---------- RMSNorm (fp32) + RoPE + bf16 cast for q,k. One wave per (n,h). ----------
__global__ __launch_bounds__(256) void k_norm_rope(
    const float* __restrict__ qkf, const float* __restrict__ qw, const float* __restrict__ kw,
    const float* __restrict__ cosT, const float* __restrict__ sinT,
    u16* __restrict__ qb, u16* __restrict__ kb)
{
  int gw = (blockIdx.x * 256 + threadIdx.x) >> 6;   // 0..65535
  int lane = threadIdx.x & 63;
  int n = gw >> 4;
  int h = gw & 15;
  float c = cosT[n * 64 + lane];
  float s = sinT[n * 64 + lane];
#pragma unroll
  for (int p = 0; p < 2; ++p) {
    const float* src = qkf + (size_t)n * 4096 + p * 2048 + h * 128;
    f32x2 xv = *(const f32x2*)(src + lane * 2);
    float xr = xv[0], xi = xv[1];
    float ss = xr * xr + xi * xi;
#pragma unroll
    for (int m = 1; m < 64; m <<= 1) ss += __shfl_xor(ss, m, 64);
    float r = 1.0f / sqrtf(ss * (1.0f / 128.0f) + 1e-6f);
    const float* wgt = p ? kw : qw;
    float yr = xr * r * wgt[lane * 2];
    float yi = xi * r * wgt[lane * 2 + 1];
    float o0 = yr * c - yi * s;
    float o1 = yr * s + yi * c;
    u16* dst = (p ? kb : qb) + (size_t)h * 4096 * 128 + (size_t)n * 128 + lane * 2;
    *(u32*)dst = ((u32)bf16_rne(o1) << 16) | bf16_rne(o0);
  }
}

// ---------- V transpose: (n, h*128+d) -> (h, d, n) ----------
__global__ __launch_bounds__(256) void k_transpose_v(const u16* __restrict__ vb, u16* __restrict__ vt) {
  __shared__ u16 Vs[64][136];
  int h = blockIdx.y;
  int n0 = blockIdx.x * 64;
  int t = threadIdx.x;
  int nl = t >> 2, d0 = (t & 3) * 32;
  const u16* src = vb + (size_t)(n0 + nl) * 2048 + h * 128 + d0;
#pragma unroll
  for (int i = 0; i < 8; ++i)
    *(u16x4*)&Vs[nl][d0 + i * 4] = *(const u16x4*)(src + i * 4);
  __syncthreads();
  int d = t >> 1, nc = (t & 1) * 32;
  u16* dst = vt + (size_t)h * 128 * 4096 + (size_t)d * 4096 + n0 + nc;
#pragma unroll
  for (int j4 = 0; j4 < 8; ++j4) {
    u16x4 o;
    o.x = Vs[nc + j4 * 4 + 0][d];
    o.y = Vs[nc + j4 * 4 + 1][d];
    o.z = Vs[nc + j4 * 4 + 2][d];
    o.w = Vs[nc + j4 * 4 + 3][d];
    *(u16x4*)(dst + j4 * 4) = o;
  }
}

// ---------- flash attention: blocks (32 q-tiles, 16 heads), 4 waves x 32 q-rows ----------
__global__ __launch_bounds__(256, 2) void k_attn(
    const u16* __restrict__ qb, const u16* __restrict__ kb, const u16* __restrict__ vt,
    u16* __restrict__ obf)
{
  __shared__ u16 Ks[64 * 128];     // XOR-swizzled rows (key-major)
  __shared__ u16 Vs[128 * 64];     // XOR-swizzled rows (d-major)
  __shared__ u16 Ps[4][32 * 72];   // per-wave P, padded stride 72
  const int t = threadIdx.x;
  const int lane = t & 63;
  const int lr = lane & 15, lg = lane >> 4;
  const int w = t >> 6;
  const int h = blockIdx.y;
  const int qw0 = blockIdx.x * 128 + w * 32;

  const u16* qh = qb + (size_t)h * 4096 * 128;
  const u16* kh = kb + (size_t)h * 4096 * 128;
  const u16* vh = vt + (size_t)h * 128 * 4096;

  s16x8 qf[2][4];
#pragma unroll
  for (int qi = 0; qi < 2; ++qi)
#pragma unroll
    for (int ks = 0; ks < 4; ++ks)
      qf[qi][ks] = *(const s16x8*)(qh + (size_t)(qw0 + qi * 16 + lr) * 128 + ks * 32 + lg * 8);

  f32x4 oacc[2][8];
#pragma unroll
  for (int i = 0; i < 2; i++)
#pragma unroll
    for (int j = 0; j < 8; j++) oacc[i][j] = f32x4{0.f, 0.f, 0.f, 0.f};
  float M[2][4], L[2][4];
#pragma unroll
  for (int i = 0; i < 2; i++)
#pragma unroll
    for (int r = 0; r < 4; r++) { M[i][r] = -__builtin_inff(); L[i][r] = 0.f; }

  const float scale_bf = bf16_to_f32(bf16_rne(0.08838834764831845f));

  for (int kt = 0; kt < 64; ++kt) {
    // stage K tile (64 keys x 128 d), source pre-swizzled so reads can XOR
#pragma unroll
    for (int i = 0; i < 4; ++i) {
      int c = t + i * 256;
      int row = c >> 4;
      int cc = (c & 15) ^ (row & 7);
      gload_lds16(kh + (size_t)(kt * 64 + row) * 128 + cc * 8, &Ks[c * 8]);
    }
    // stage V^T tile (128 d x 64 keys)
#pragma unroll
    for (int i = 0; i < 4; ++i) {
      int c = t + i * 256;
      int d = c >> 3;
      int cc = (c & 7) ^ (d & 7);
      gload_lds16(vh + (size_t)d * 4096 + kt * 64 + cc * 8, &Vs[c * 8]);
    }
    __syncthreads();

    // S = Q . K^T  (2 q-blocks x 4 key-blocks of 16x16)
    f32x4 sfr[2][4];
#pragma unroll
    for (int qi = 0; qi < 2; ++qi)
#pragma unroll
      for (int kbl = 0; kbl < 4; ++kbl) {
        f32x4 a = f32x4{0.f, 0.f, 0.f, 0.f};
#pragma unroll
        for (int ks = 0; ks < 4; ++ks) {
          int key = kbl * 16 + lr;
          int byteoff = (key * 256 + (ks * 32 + lg * 8) * 2) ^ ((key & 7) << 4);
          s16x8 bfr = *(const s16x8*)((const char*)Ks + byteoff);
          a = __builtin_amdgcn_mfma_f32_16x16x32_bf16(qf[qi][ks], bfr, a, 0, 0, 0);
        }
        sfr[qi][kbl] = a;
      }

    // online softmax (scores rounded to bf16, * bf16(scale), rounded again -> matches ref)
#pragma unroll
    for (int qi = 0; qi < 2; ++qi) {
      float fac[4];
#pragma unroll
      for (int r = 0; r < 4; ++r) {
#pragma unroll
        for (int kbl = 0; kbl < 4; ++kbl) {
          float sv = bf16_to_f32(bf16_rne(sfr[qi][kbl][r])) * scale_bf;
          sfr[qi][kbl][r] = bf16_to_f32(bf16_rne(sv));
        }
        float mx = fmaxf(fmaxf(sfr[qi][0][r], sfr[qi][1][r]), fmaxf(sfr[qi][2][r], sfr[qi][3][r]));
#pragma unroll
        for (int m = 1; m < 16; m <<= 1) mx = fmaxf(mx, __shfl_xor(mx, m, 64));
        float newM = fmaxf(M[qi][r], mx);
        fac[r] = expf(M[qi][r] - newM);
        M[qi][r] = newM;
      }
      float sum[4] = {0.f, 0.f, 0.f, 0.f};
#pragma unroll
      for (int kbl = 0; kbl < 4; ++kbl)
#pragma unroll
        for (int r = 0; r < 4; ++r) {
          float p = expf(sfr[qi][kbl][r] - M[qi][r]);
          sum[r] += p;
          Ps[w][(qi * 16 + lg * 4 + r) * 72 + kbl * 16 + lr] = bf16_rne(p);
        }
#pragma unroll
      for (int r = 0; r < 4; ++r) {
        float s4 = sum[r];
#pragma unroll
        for (int m = 1; m < 16; m <<= 1) s4 += __shfl_xor(s4, m, 64);
        L[qi][r] = L[qi][r] * fac[r] + s4;
      }
#pragma unroll
      for (int db = 0; db < 8; ++db)
#pragma unroll
        for (int r = 0; r < 4; ++r)
          oacc[qi][db][r] *= fac[r];
    }

    asm volatile("s_waitcnt lgkmcnt(0)" ::: "memory");   // P writes visible before cross-lane reads

    // PV: O += P (32x64) . V (64x128)
    s16x8 pa[2][2];
#pragma unroll
    for (int qi = 0; qi < 2; ++qi)
#pragma unroll
      for (int ks = 0; ks < 2; ++ks)
        pa[qi][ks] = *(const s16x8*)&Ps[w][(qi * 16 + lr) * 72 + ks * 32 + lg * 8];
#pragma unroll
    for (int db = 0; db < 8; ++db)
#pragma unroll
      for (int ks = 0; ks < 2; ++ks) {
        int d = db * 16 + lr;
        int byteoff = (d * 128 + (ks * 32 + lg * 8) * 2) ^ ((d & 7) << 4);
        s16x8 vb8 = *(const s16x8*)((const char*)Vs + byteoff);
        oacc[0][db] = __builtin_amdgcn_mfma_f32_16x16x32_bf16(pa[0][ks], vb8, oacc[0][db], 0, 0, 0);
        oacc[1][db] = __builtin_amdgcn_mfma_f32_16x16x32_bf16(pa[1][ks], vb8, oacc[1][db], 0, 0, 0);
      }
    __syncthreads();
  }

  // normalize + store bf16 (n, h*128+d)
#pragma unroll
  for (int qi = 0; qi < 2; ++qi) {
    float rl[4];
#pragma unroll
    for (int r = 0; r < 4; ++r) rl[r] = 1.0f / L[qi][r];
#pragma unroll
    for (int db = 0; db < 8; ++db) {
      int d = db * 16 + lr;
#pragma unroll
      for (int r = 0; r < 4; ++r) {
        int q = qw0 + qi * 16 + lg * 4 + r;
        obf[(size_t)q * 2048 + h * 128 + d] = bf16_rne(oacc[qi][db][r] * rl[r]);
      }
    }
  }
}

// ---------- launch ----------
extern "C" void kernel_launch(void* const* d_in, const int* in_sizes, int n_in,
                              void* d_out, int out_size, void* d_ws, size_t ws_size,
                              hipStream_t stream) {
  const float* x      = (const float*)d_in[0];
  const float* qkv_w  = (const float*)d_in[1];
  const float* qkv_b  = (const float*)d_in[2];
  const float* qnw    = (const float*)d_in[3];
  const float* knw    = (const float*)d_in[4];
  const float* proj_w = (const float*)d_in[5];
  const float* proj_b = (const float*)d_in[6];
  float* out = (float*)d_out;
  char* ws = (char*)d_ws;

  u16* xs    = (u16*)(ws + OFF_XSPLIT);
  u16* wsp   = (u16*)(ws + OFF_WSPLIT);
  u16* pws   = (u16*)(ws + OFF_WSPLIT);   // reuse (after QKV GEMM)
  float* qkf = (float*)(ws + OFF_QKF);
  u16* vb16  = (u16*)(ws + OFF_VB);
  u16* qb16  = (u16*)(ws + OFF_QB);
  u16* kb16  = (u16*)(ws + OFF_KB);
  u16* vt16  = (u16*)(ws + OFF_VT);
  u16* obf   = (u16*)(ws + OFF_XSPLIT);   // reuse (x dead after QKV GEMM)
  float* cosT = (float*)(ws + OFF_COS);
  float* sinT = (float*)(ws + OFF_SIN);

  k_split<<<2048, 256, 0, stream>>>(x, xs, xs + (size_t)4096 * 2048, 4096 * 2048);
  k_split<<<2048, 256, 0, stream>>>(qkv_w, wsp, wsp + (size_t)6144 * 2048, 6144 * 2048);
  k_rope_table<<<1024, 256, 0, stream>>>(cosT, sinT);

  // QKV: Xh.Wh + Xh.Wl + Xl.Wh
  k_gemm<0><<<dim3(48, 32), 256, 0, stream>>>(xs, xs, xs + (size_t)4096 * 2048,
                                              wsp, wsp + (size_t)6144 * 2048, wsp,
                                              3, 2048, qkv_b, qkf, vb16);

  k_split<<<2048, 256, 0, stream>>>(proj_w, pws, pws + (size_t)2048 * 2048, 2048 * 2048);
  k_norm_rope<<<16384, 256, 0, stream>>>(qkf, qnw, knw, cosT, sinT, qb16, kb16);
  k_transpose_v<<<dim3(64, 16), 256, 0, stream>>>(vb16, vt16);
  k_attn<<<dim3(32, 16), 256, 0, stream>>>(qb16, kb16, vt16, obf);

  // proj: O.Ph + O.Pl  (O is exactly bf16)
  k_gemm<1><<<dim3(16, 32), 256, 0, stream>>>(obf, obf, obf,
                                              pws, pws + (size_t)2048 * 2048, pws,
                                              2, 2048, proj_b, out, nullptr);
}

// Round 2
// 806.423 us; speedup vs baseline: 1.1138x; 1.1138x over previous
//
#include <hip/hip_runtime.h>
#include <hip/hip_bf16.h>

typedef unsigned short u16;
typedef unsigned int u32;
typedef __attribute__((ext_vector_type(8))) short s16x8;
typedef __attribute__((ext_vector_type(4))) float f32x4;
typedef __attribute__((ext_vector_type(2))) float f32x2;
typedef __attribute__((ext_vector_type(4))) unsigned short u16x4;

#define DEV static __device__ __forceinline__

// ---------- helpers ----------
DEV u16 bf16_rne(float f) {
  u32 u = __float_as_uint(f);
  u32 r = 0x7FFFu + ((u >> 16) & 1u);
  return (u16)((u + r) >> 16);
}
DEV float bf16_to_f32(u16 h) { return __uint_as_float(((u32)h) << 16); }

typedef const __attribute__((address_space(1))) u32* gptr_t;
typedef __attribute__((address_space(3))) u32* lptr_t;
DEV void gload_lds16(const void* g, void* l) {
  __builtin_amdgcn_global_load_lds((gptr_t)g, (lptr_t)l, 16, 0, 0);
}

// ---------- workspace layout (bytes) ----------
#define OFF_XSPLIT  0ull                       // 2 * 4096*2048 u16 = 33,554,432   (Xh | Xl)
#define OFF_WSPLIT  33554432ull                // 2 * 6144*2048 u16 = 50,331,648   (Wh | Wl) ; reused later for (Ph | Pl)
#define OFF_QKF     83886080ull                // 4096*4096 f32 = 67,108,864       ([q|k] fp32 per row)
#define OFF_VB      150994944ull               // 4096*2048 u16 = 16,777,216       v bf16 (n,h,d)
#define OFF_QB      167772160ull               // 16,777,216                       q bf16 (h,n,d)
#define OFF_KB      184549376ull               // 16,777,216                       k bf16 (h,n,d)
#define OFF_VT      201326592ull               // 16,777,216                       v bf16 (h,d,n)
#define OFF_COS     218103808ull               // 4096*64 f32 = 1,048,576
#define OFF_SIN     219152384ull               // 1,048,576
// OBF (attention out bf16, (n,2048)) reuses OFF_XSPLIT (x dead after QKV GEMM)

// ---------- split fp32 -> bf16 hi + bf16 lo ----------
__global__ __launch_bounds__(256) void k_split(const float* __restrict__ in,
                                               u16* __restrict__ hi, u16* __restrict__ lo, int n) {
  int i = blockIdx.x * 256 + threadIdx.x;
  int stride = gridDim.x * 256;
  for (; i < n; i += stride) {
    float x = in[i];
    u16 h = bf16_rne(x);
    float xh = bf16_to_f32(h);
    hi[i] = h;
    lo[i] = bf16_rne(x - xh);
  }
}

// ---------- RoPE cos/sin table: (n, 64) ----------
__global__ __launch_bounds__(256) void k_rope_table(float* __restrict__ cosT, float* __restrict__ sinT) {
  int tid = blockIdx.x * 256 + threadIdx.x;
  if (tid >= 4096 * 64) return;
  int n = tid >> 6, j = tid & 63;
  int t = n >> 9, hh = (n >> 5) & 15, ww = n & 31;
  float pos, e;
  if (j < 32)      { pos = (float)t;  e = (float)j * (1.0f / 32.0f); }
  else if (j < 48) { pos = (float)hh; e = (float)(j - 32) * (1.0f / 16.0f); }
  else             { pos = (float)ww; e = (float)(j - 48) * (1.0f / 16.0f); }
  float inv = (float)pow(10000.0, -(double)e);
  float f = pos * inv;
  cosT[tid] = cosf(f);
  sinT[tid] = sinf(f);
}

// ---------- bf16 GEMM, m97 structure: 128x128 tile, BK=32, 4 waves ----------
template<int MODE>
__global__ __launch_bounds__(256, 2) void k_gemm(
    const u16* __restrict__ A0, const u16* __restrict__ A1, const u16* __restrict__ A2,
    const u16* __restrict__ B0, const u16* __restrict__ B1, const u16* __restrict__ B2,
    int nseg, int K,
    const float* __restrict__ bias,
    float* __restrict__ outF, u16* __restrict__ outV)
{
  __shared__ u16 As[128 * 32];
  __shared__ u16 Bs[128 * 32];
  const int t = threadIdx.x;
  const int lane = t & 63;
  const int lr = lane & 15, lg = lane >> 4;
  const int w = t >> 6;
  const int wr = w >> 1, wc = w & 1;
  const int row0 = blockIdx.y * 128;
  const int col0 = blockIdx.x * 128;

  f32x4 acc[4][4];
#pragma unroll
  for (int m = 0; m < 4; m++)
#pragma unroll
    for (int n = 0; n < 4; n++) acc[m][n] = f32x4{0.f, 0.f, 0.f, 0.f};

  const int c0 = t, c1 = t + 256;

  for (int s = 0; s < nseg; ++s) {
    const u16* Ab = (s == 0) ? A0 : (s == 1) ? A1 : A2;
    const u16* Bb = (s == 0) ? B0 : (s == 1) ? B1 : B2;
    const int nkb = K / 32;
    for (int kb = 0; kb < nkb; ++kb) {
      const int k0 = kb * 32;
      gload_lds16(Ab + (size_t)(row0 + (c0 >> 2)) * K + k0 + (c0 & 3) * 8, &As[c0 * 8]);
      gload_lds16(Ab + (size_t)(row0 + (c1 >> 2)) * K + k0 + (c1 & 3) * 8, &As[c1 * 8]);
      gload_lds16(Bb + (size_t)(col0 + (c0 >> 2)) * K + k0 + (c0 & 3) * 8, &Bs[c0 * 8]);
      gload_lds16(Bb + (size_t)(col0 + (c1 >> 2)) * K + k0 + (c1 & 3) * 8, &Bs[c1 * 8]);
      __syncthreads();
      s16x8 af[4], bf[4];
#pragma unroll
      for (int m = 0; m < 4; m++)
        af[m] = *(const s16x8*)&As[(wr * 64 + m * 16 + lr) * 32 + lg * 8];
#pragma unroll
      for (int n = 0; n < 4; n++)
        bf[n] = *(const s16x8*)&Bs[(wc * 64 + n * 16 + lr) * 32 + lg * 8];
      __builtin_amdgcn_s_setprio(1);
#pragma unroll
      for (int m = 0; m < 4; m++)
#pragma unroll
        for (int n = 0; n < 4; n++)
          acc[m][n] = __builtin_amdgcn_mfma_f32_16x16x32_bf16(af[m], bf[n], acc[m][n], 0, 0, 0);
      __builtin_amdgcn_s_setprio(0);
      __syncthreads();
    }
  }

#pragma unroll
  for (int m = 0; m < 4; m++) {
#pragma unroll
    for (int n = 0; n < 4; n++) {
      int col = col0 + wc * 64 + n * 16 + lr;
      float b = bias[col];
#pragma unroll
      for (int r = 0; r < 4; r++) {
        int row = row0 + wr * 64 + m * 16 + lg * 4 + r;
        float v = acc[m][n][r] + b;
        if constexpr (MODE == 0) {
          if (col < 4096) outF[(size_t)row * 4096 + col] = v;
          else            outV[(size_t)row * 2048 + (col - 4096)] = bf16_rne(v);
        } else {
          outF[(size_t)row * 2048 + col] = v;
        }
      }
    }
  }
}

// ---------- RMSNorm (fp32) + RoPE + bf16 cast for q,k. One wave per (n,h). ----------
__global__ __launch_bounds__(256) void k_norm_rope(
    const float* __restrict__ qkf, const float* __restrict__ qw, const float* __restrict__ kw,
    const float* __restrict__ cosT, const float* __restrict__ sinT,
    u16* __restrict__ qb, u16* __restrict__ kb)
{
  int gw = (blockIdx.x * 256 + threadIdx.x) >> 6;
  int lane = threadIdx.x & 63;
  int n = gw >> 4;
  int h = gw & 15;
  float c = cosT[n * 64 + lane];
  float s = sinT[n * 64 + lane];
#pragma unroll
  for (int p = 0; p < 2; ++p) {
    const float* src = qkf + (size_t)n * 4096 + p * 2048 + h * 128;
    f32x2 xv = *(const f32x2*)(src + lane * 2);
    float xr = xv[0], xi = xv[1];
    float ss = xr * xr + xi * xi;
#pragma unroll
    for (int m = 1; m < 64; m <<= 1) ss += __shfl_xor(ss, m, 64);
    float r = 1.0f / sqrtf(ss * (1.0f / 128.0f) + 1e-6f);
    const float* wgt = p ? kw : qw;
    float yr = xr * r * wgt[lane * 2];
    float yi = xi * r * wgt[lane * 2 + 1];
    float o0 = yr * c - yi * s;
    float o1 = yr * s + yi * c;
    u16* dst = (p ? kb : qb) + (size_t)h * 4096 * 128 + (size_t)n * 128 + lane * 2;
    *(u32*)dst = ((u32)bf16_rne(o1) << 16) | bf16_rne(o0);
  }
}

// ---------- V transpose: (n, h*128+d) -> (h, d, n) ----------
__global__ __launch_bounds__(256) void k_transpose_v(const u16* __restrict__ vb, u16* __restrict__ vt) {
  __shared__ u16 Vs[64][136];
  int h = blockIdx.y;
  int n0 = blockIdx.x * 64;
  int t = threadIdx.x;
  int nl = t >> 2, d0 = (t & 3) * 32;
  const u16* src = vb + (size_t)(n0 + nl) * 2048 + h * 128 + d0;
#pragma unroll
  for (int i = 0; i < 8; ++i)
    *(u16x4*)&Vs[nl][d0 + i * 4] = *(const u16x4*)(src + i * 4);
  __syncthreads();
  int d = t >> 1, nc = (t & 1) * 32;
  u16* dst = vt + (size_t)h * 128 * 4096 + (size_t)d * 4096 + n0 + nc;
#pragma unroll
  for (int j4 = 0; j4 < 8; ++j4) {
    u16x4 o;
    o.x = Vs[nc + j4 * 4 + 0][d];
    o.y = Vs[nc + j4 * 4 + 1][d];
    o.z = Vs[nc + j4 * 4 + 2][d];
    o.w = Vs[nc + j4 * 4 + 3][d];
    *(u16x4*)(dst + j4 * 4) = o;
  }
}

// ---------- flash attention: blocks (32 q-tiles, 16 heads), 4 waves x 32 q-rows ----------
__global__ __launch_bounds__(256, 2) void k_attn(
    const u16* __restrict__ qb, const u16* __restrict__ kb, const u16* __restrict__ vt,
    u16* __restrict__ obf)
{
  __shared__ u16 Ks[64 * 128];     // XOR-swizzled rows (key-major)
  __shared__ u16 Vs[128 * 64];     // XOR-swizzled rows (d-major)
  __shared__ u16 Ps[4][32 * 72];   // per-wave P, padded stride 72
  const int t = threadIdx.x;
  const int lane = t & 63;
  const int lr = lane & 15, lg = lane >> 4;
  const int w = t >> 6;
  const int h = blockIdx.y;
  const int qw0 = blockIdx.x * 128 + w * 32;

  const u16* qh = qb + (size_t)h * 4096 * 128;
  const u16* kh = kb + (size_t)h * 4096 * 128;
  const u16* vh = vt + (size_t)h * 128 * 4096;

  s16x8 qf[2][4];
#pragma unroll
  for (int qi = 0; qi < 2; ++qi)
#pragma unroll
    for (int ks = 0; ks < 4; ++ks)
      qf[qi][ks] = *(const s16x8*)(qh + (size_t)(qw0 + qi * 16 + lr) * 128 + ks * 32 + lg * 8);

  f32x4 oacc[2][8];
#pragma unroll
  for (int i = 0; i < 2; i++)
#pragma unroll
    for (int j = 0; j < 8; j++) oacc[i][j] = f32x4{0.f, 0.f, 0.f, 0.f};
  float M[2][4], L[2][4];
#pragma unroll
  for (int i = 0; i < 2; i++)
#pragma unroll
    for (int r = 0; r < 4; r++) { M[i][r] = -__builtin_inff(); L[i][r] = 0.f; }

  const float scale_bf = bf16_to_f32(bf16_rne(0.08838834764831845f));

  for (int kt = 0; kt < 64; ++kt) {
    // stage K tile (64 keys x 128 d), source pre-swizzled so reads can XOR
#pragma unroll
    for (int i = 0; i < 4; ++i) {
      int c = t + i * 256;
      int row = c >> 4;
      int cc = (c & 15) ^ (row & 7);
      gload_lds16(kh + (size_t)(kt * 64 + row) * 128 + cc * 8, &Ks[c * 8]);
    }
    // stage V^T tile (128 d x 64 keys)
#pragma unroll
    for (int i = 0; i < 4; ++i) {
      int c = t + i * 256;
      int d = c >> 3;
      int cc = (c & 7) ^ (d & 7);
      gload_lds16(vh + (size_t)d * 4096 + kt * 64 + cc * 8, &Vs[c * 8]);
    }
    __syncthreads();

    // S = Q . K^T  (2 q-blocks x 4 key-blocks of 16x16)
    f32x4 sfr[2][4];
    __builtin_amdgcn_s_setprio(1);
#pragma unroll
    for (int qi = 0; qi < 2; ++qi)
#pragma unroll
      for (int kbl = 0; kbl < 4; ++kbl) {
        f32x4 a = f32x4{0.f, 0.f, 0.f, 0.f};
#pragma unroll
        for (int ks = 0; ks < 4; ++ks) {
          int key = kbl * 16 + lr;
          int byteoff = (key * 256 + (ks * 32 + lg * 8) * 2) ^ ((key & 7) << 4);
          s16x8 bfr = *(const s16x8*)((const char*)Ks + byteoff);
          a = __builtin_amdgcn_mfma_f32_16x16x32_bf16(qf[qi][ks], bfr, a, 0, 0, 0);
        }
        sfr[qi][kbl] = a;
      }
    __builtin_amdgcn_s_setprio(0);

    // online softmax; scores double-rounded to bf16 (matches ref), native exp,
    // defer-max (T13, THR=8): skip O/L rescale while max growth <= 8.
#pragma unroll
    for (int qi = 0; qi < 2; ++qi) {
      float mx[4];
#pragma unroll
      for (int r = 0; r < 4; ++r) {
#pragma unroll
        for (int kbl = 0; kbl < 4; ++kbl) {
          float sv = bf16_to_f32(bf16_rne(sfr[qi][kbl][r])) * scale_bf;
          sfr[qi][kbl][r] = bf16_to_f32(bf16_rne(sv));
        }
        float m0 = fmaxf(fmaxf(sfr[qi][0][r], sfr[qi][1][r]), fmaxf(sfr[qi][2][r], sfr[qi][3][r]));
#pragma unroll
        for (int m = 1; m < 16; m <<= 1) m0 = fmaxf(m0, __shfl_xor(m0, m, 64));
        mx[r] = m0;
      }
      bool ok = (mx[0] - M[qi][0] <= 8.f) && (mx[1] - M[qi][1] <= 8.f) &&
                (mx[2] - M[qi][2] <= 8.f) && (mx[3] - M[qi][3] <= 8.f);
      if (!__all(ok)) {
#pragma unroll
        for (int r = 0; r < 4; ++r) {
          float nm = fmaxf(M[qi][r], mx[r]);
          float fac = __expf(M[qi][r] - nm);
          M[qi][r] = nm;
          L[qi][r] *= fac;
#pragma unroll
          for (int db = 0; db < 8; ++db) oacc[qi][db][r] *= fac;
        }
      }
      float sum[4] = {0.f, 0.f, 0.f, 0.f};
#pragma unroll
      for (int kbl = 0; kbl < 4; ++kbl)
#pragma unroll
        for (int r = 0; r < 4; ++r) {
          float p = __expf(sfr[qi][kbl][r] - M[qi][r]);
          sum[r] += p;
          Ps[w][(qi * 16 + lg * 4 + r) * 72 + kbl * 16 + lr] = bf16_rne(p);
        }
#pragma unroll
      for (int r = 0; r < 4; ++r) {
        float s4 = sum[r];
#pragma unroll
        for (int m = 1; m < 16; m <<= 1) s4 += __shfl_xor(s4, m, 64);
        L[qi][r] += s4;
      }
    }

    asm volatile("s_waitcnt lgkmcnt(0)" ::: "memory");   // P writes visible before cross-lane reads

    // PV: O += P (32x64) . V (64x128)
    s16x8 pa[2][2];
#pragma unroll
    for (int qi = 0; qi < 2; ++qi)
#pragma unroll
      for (int ks = 0; ks < 2; ++ks)
        pa[qi][ks] = *(const s16x8*)&Ps[w][(qi * 16 + lr) * 72 + ks * 32 + lg * 8];
    __builtin_amdgcn_s_setprio(1);
#pragma unroll
    for (int db = 0; db < 8; ++db)
#pragma unroll
      for (int ks = 0; ks < 2; ++ks) {
        int d = db * 16 + lr;
        int byteoff = (d * 128 + (ks * 32 + lg * 8) * 2) ^ ((d & 7) << 4);
        s16x8 vb8 = *(const s16x8*)((const char*)Vs + byteoff);
        oacc[0][db] = __builtin_amdgcn_mfma_f32_16x16x32_bf16(pa[0][ks], vb8, oacc[0][db], 0, 0, 0);
        oacc[1][db] = __builtin_amdgcn_mfma_f32_16x16x32_bf16(pa[1][ks], vb8, oacc[1][db], 0, 0, 0);
      }
    __builtin_amdgcn_s_setprio(0);
    __syncthreads();
  }

  // normalize + store bf16 (n, h*128+d)
#pragma unroll
  for (int qi = 0; qi < 2; ++qi) {
    float rl[4];
#pragma unroll
    for (int r = 0; r < 4; ++r) rl[r] = 1.0f / L[qi][r];
#pragma unroll
    for (int db = 0; db < 8; ++db) {
      int d = db * 16 + lr;
#pragma unroll
      for (int r = 0; r < 4; ++r) {
        int q = qw0 + qi * 16 + lg * 4 + r;
        obf[(size_t)q * 2048 + h * 128 + d] = bf16_rne(oacc[qi][db][r] * rl[r]);
      }
    }
  }
}

// ---------- launch ----------
extern "C" void kernel_launch(void* const* d_in, const int* in_sizes, int n_in,
                              void* d_out, int out_size, void* d_ws, size_t ws_size,
                              hipStream_t stream) {
  const float* x      = (const float*)d_in[0];
  const float* qkv_w  = (const float*)d_in[1];
  const float* qkv_b  = (const float*)d_in[2];
  const float* qnw    = (const float*)d_in[3];
  const float* knw    = (const float*)d_in[4];
  const float* proj_w = (const float*)d_in[5];
  const float* proj_b = (const float*)d_in[6];
  float* out = (float*)d_out;
  char* ws = (char*)d_ws;

  u16* xs    = (u16*)(ws + OFF_XSPLIT);
  u16* wsp   = (u16*)(ws + OFF_WSPLIT);
  u16* pws   = (u16*)(ws + OFF_WSPLIT);
  float* qkf = (float*)(ws + OFF_QKF);
  u16* vb16  = (u16*)(ws + OFF_VB);
  u16* qb16  = (u16*)(ws + OFF_QB);
  u16* kb16  = (u16*)(ws + OFF_KB);
  u16* vt16  = (u16*)(ws + OFF_VT);
  u16* obf   = (u16*)(ws + OFF_XSPLIT);
  float* cosT = (float*)(ws + OFF_COS);
  float* sinT = (float*)(ws + OFF_SIN);

  k_split<<<2048, 256, 0, stream>>>(x, xs, xs + (size_t)4096 * 2048, 4096 * 2048);
  k_split<<<2048, 256, 0, stream>>>(qkv_w, wsp, wsp + (size_t)6144 * 2048, 6144 * 2048);
  k_rope_table<<<1024, 256, 0, stream>>>(cosT, sinT);

  // QKV: Xh.Wh + Xh.Wl + Xl.Wh
  k_gemm<0><<<dim3(48, 32), 256, 0, stream>>>(xs, xs, xs + (size_t)4096 * 2048,
                                              wsp, wsp + (size_t)6144 * 2048, wsp,
                                              3, 2048, qkv_b, qkf, vb16);

  k_split<<<2048, 256, 0, stream>>>(proj_w, pws, pws + (size_t)2048 * 2048, 2048 * 2048);
  k_norm_rope<<<16384, 256, 0, stream>>>(qkf, qnw, knw, cosT, sinT, qb16, kb16);
  k_transpose_v<<<dim3(64, 16), 256, 0, stream>>>(vb16, vt16);
  k_attn<<<dim3(32, 16), 256, 0, stream>>>(qb16, kb16, vt16, obf);

  // proj: O.Ph + O.Pl  (O is exactly bf16)
  k_gemm<1><<<dim3(16, 32), 256, 0, stream>>>(obf, obf, obf,
                                              pws, pws + (size_t)2048 * 2048, pws,
                                              2, 2048, proj_b, out, nullptr);
}